// Round 15
// baseline (78.054 us; speedup 1.0000x reference)
//
#include <hip/hip_runtime.h>
#include <math.h>

#define C_IN  128
#define C_HID 256
#define HGT   64
#define WID   128
#define NBATCH 16
#define HW (HGT * WID)

typedef unsigned int   uint32;
typedef unsigned short u16;
typedef float f32x4  __attribute__((ext_vector_type(4)));
typedef short bf16x8 __attribute__((ext_vector_type(8)));

__device__ __forceinline__ uint32 f2bf_bits(float f) {
    uint32 u = __float_as_uint(f);
    u = (u + 0x7fff + ((u >> 16) & 1)) >> 16;   // RNE
    return u;
}
__device__ __forceinline__ float bf_lo(uint32 v) { return __uint_as_float(v << 16); }
__device__ __forceinline__ float bf_hi(uint32 v) { return __uint_as_float(v & 0xffff0000u); }
__device__ __forceinline__ float bf_u16(u16 v)   { return __uint_as_float(((uint32)v) << 16); }

// ============ quant: per-tensor symmetric int8 fake-quant + repack ============
// 1024 threads; max phase uses f32x4 loads (all tensor sizes divisible by 4).
__global__ __launch_bounds__(1024) void quant4_kernel(
    const float* __restrict__ dw1, const float* __restrict__ pw1,
    const float* __restrict__ dw2, const float* __restrict__ pw2,
    const float* __restrict__ db2,
    float* __restrict__ qdw1T, u16* __restrict__ Blin,
    float* __restrict__ qdw2T, float* __restrict__ qpw2,
    float* __restrict__ scales)
{
    const float* w; int n;
    switch (blockIdx.x) {
        case 0:  w = dw1; n = C_IN * 9;    break;
        case 1:  w = pw1; n = C_HID * C_IN; break;
        case 2:  w = dw2; n = C_HID * 9;   break;
        default: w = pw2; n = 2 * C_HID;   break;
    }
    __shared__ float sm[1024];
    int tid = threadIdx.x;
    const f32x4* w4 = (const f32x4*)w;
    int n4 = n >> 2;
    float m = 0.0f;
    #pragma unroll 4
    for (int i = tid; i < n4; i += 1024) {
        f32x4 v = w4[i];
        m = fmaxf(m, fmaxf(fmaxf(fabsf(v.x), fabsf(v.y)),
                           fmaxf(fabsf(v.z), fabsf(v.w))));
    }
    sm[tid] = m;
    __syncthreads();
    for (int s = 512; s > 0; s >>= 1) {
        if (tid < s) sm[tid] = fmaxf(sm[tid], sm[tid + s]);
        __syncthreads();
    }
    const float scale = sm[0] / 127.0f;

    if (blockIdx.x == 0) {
        for (int i = tid; i < C_IN * 9; i += 1024) {
            int t = i >> 7, cin = i & 127;
            float v = rintf(dw1[cin * 9 + t] / scale);
            v = fminf(fmaxf(v, -128.0f), 127.0f);
            qdw1T[i] = v * scale;
        }
    } else if (blockIdx.x == 1) {
        if (tid == 0) scales[0] = scale;
        // slot s = (kstep*16 + cofrag)*64 + lane; each slot = 8 bf16 (16B)
        #pragma unroll
        for (int i = tid; i < 4096; i += 1024) {
            int kstep = i >> 10;
            int cf    = (i >> 6) & 15;
            int l     = i & 63;
            int co    = cf * 16 + (l & 15);
            int k0    = kstep * 32 + ((l >> 4) << 3);
            const float* src = pw1 + (size_t)co * C_IN + k0;
            f32x4 a = *(const f32x4*)src;
            f32x4 b = *(const f32x4*)(src + 4);
            float vv[8] = {a.x, a.y, a.z, a.w, b.x, b.y, b.z, b.w};
            uint32 pk[4];
            #pragma unroll
            for (int p = 0; p < 4; ++p) {
                float v0 = fminf(fmaxf(rintf(vv[2 * p]     / scale), -128.0f), 127.0f);
                float v1 = fminf(fmaxf(rintf(vv[2 * p + 1] / scale), -128.0f), 127.0f);
                pk[p] = f2bf_bits(v0) | (f2bf_bits(v1) << 16);   // ints exact in bf16
            }
            ((uint4*)Blin)[i] = make_uint4(pk[0], pk[1], pk[2], pk[3]);
        }
    } else if (blockIdx.x == 2) {
        for (int i = tid; i < C_HID * 9; i += 1024) {
            int t = i >> 8, ch = i & 255;
            float v = rintf(dw2[ch * 9 + t] / scale);
            v = fminf(fmaxf(v, -128.0f), 127.0f);
            qdw2T[i] = v * scale;
        }
    } else {
        if (tid < 2 * C_HID) {
            float v = rintf(pw2[tid] / scale);
            v = fminf(fmaxf(v, -128.0f), 127.0f);
            qpw2[tid] = v * scale;
        }
        // dotbias[o] = sum_ch qpw2[o][ch] * db2[ch]  (dw2 bias folded through pw2)
        #pragma unroll
        for (int o = 0; o < 2; ++o) {
            __syncthreads();
            if (tid < 256) {
                float qv = rintf(pw2[o * C_HID + tid] / scale);
                qv = fminf(fmaxf(qv, -128.0f), 127.0f) * scale;
                sm[tid] = qv * db2[tid];
            }
            __syncthreads();
            for (int s = 128; s > 0; s >>= 1) {
                if (tid < s) sm[tid] += sm[tid + s];
                __syncthreads();
            }
            if (tid == 0) scales[1 + o] = sm[0];
        }
    }
}

// ============ fused: dw1 + MFMA pw1 + ReLU + dw2/pw2 partials -> Pg ============
// R14 structure with pipelined phase 1. launch_bounds (512,2): LDS already caps
// occupancy at 2 blocks/CU, so the allocator can spend ~128 VGPRs on the
// 2-buffer pipeline without losing a single wave of achieved occupancy.
__global__ __launch_bounds__(512, 2) void fused_main(
    const float* __restrict__ x,
    const float* __restrict__ qdw1T, const float* __restrict__ db1,
    const u16* __restrict__ Blin, const float* __restrict__ pb1,
    const float* __restrict__ qdw2T, const float* __restrict__ qpw2,
    const float* __restrict__ scales,
    float* __restrict__ Pg)
{
    __shared__ __align__(16) unsigned char smem_raw[C_HID * 132 * 2];   // 67584 B
    __shared__ float wlds[9 * C_HID + 2 * C_HID];                        // 11264 B
    u16 (*h1s)[136] = (u16 (*)[136])smem_raw;   // phase 1-2: bf16 A-tile (34.8 KB)
    u16 (*h2s)[132] = (u16 (*)[132])smem_raw;   // epilogue+phase 3: full h2 row
    float* Pbuf = (float*)smem_raw;             // phase 4: [6][8][128] reduce buffer

    const int bid = blockIdx.x;
    const int swz = (bid & 7) * 128 + (bid >> 3);   // XCD-bijective
    const int nb  = swz >> 6;
    const int y   = swz & 63;                        // this block's h2 row z
    const int tid = threadIdx.x;
    const int wave = tid >> 6, lane = tid & 63;

    // ---------- phase 1: depthwise 1 -> h1s (pipelined 2-buffer; halo via shfl) ----------
    {
        const int q = tid & 31, g = tid >> 5;
        const int px0 = q << 2, cin0 = g << 3;
        // lane = (g&1)*32 + q: q boundaries coincide with half-wave boundaries,
        // so cross-boundary shuffle values are always masked to zero.

        float a32[8][4];
        {
            f32x4 bia = *(const f32x4*)(db1 + cin0);
            f32x4 bib = *(const f32x4*)(db1 + cin0 + 4);
            #pragma unroll
            for (int c = 0; c < 8; ++c) {
                float b = (c < 4) ? ((const float*)&bia)[c] : ((const float*)&bib)[c - 4];
                #pragma unroll
                for (int p = 0; p < 4; ++p) a32[c][p] = b;
            }
        }

        float msk[3]; const float* bky[3];
        #pragma unroll
        for (int ky = 0; ky < 3; ++ky) {
            int yy = y + ky - 1;
            msk[ky] = (yy >= 0 && yy < HGT) ? 1.0f : 0.0f;
            int yc = min(max(yy, 0), HGT - 1);
            bky[ky] = x + (((size_t)nb * C_IN + cin0) * HGT + yc) * WID + px0;
        }

        f32x4 A[8], B[8];
        #pragma unroll
        for (int c = 0; c < 8; ++c) A[c] = *(const f32x4*)(bky[0] + (size_t)c * HW);
        #pragma unroll
        for (int c = 0; c < 8; ++c) B[c] = *(const f32x4*)(bky[1] + (size_t)c * HW);

        auto compute = [&](int ky, f32x4* mid) {
            float w3[3][8];
            #pragma unroll
            for (int kx = 0; kx < 3; ++kx) {
                f32x4 wa = *(const f32x4*)(qdw1T + (ky * 3 + kx) * C_IN + cin0);
                f32x4 wb = *(const f32x4*)(qdw1T + (ky * 3 + kx) * C_IN + cin0 + 4);
                w3[kx][0] = wa.x * msk[ky]; w3[kx][1] = wa.y * msk[ky];
                w3[kx][2] = wa.z * msk[ky]; w3[kx][3] = wa.w * msk[ky];
                w3[kx][4] = wb.x * msk[ky]; w3[kx][5] = wb.y * msk[ky];
                w3[kx][6] = wb.z * msk[ky]; w3[kx][7] = wb.w * msk[ky];
            }
            #pragma unroll
            for (int c = 0; c < 8; ++c) {
                float lf = __shfl_up(mid[c].w, 1);     // lane-1's px0-1
                float rt = __shfl_down(mid[c].x, 1);   // lane+1's px0+4
                lf = (q > 0)  ? lf : 0.0f;
                rt = (q < 31) ? rt : 0.0f;
                float seg[6] = {lf, mid[c].x, mid[c].y, mid[c].z, mid[c].w, rt};
                #pragma unroll
                for (int kx = 0; kx < 3; ++kx)
                    #pragma unroll
                    for (int p = 0; p < 4; ++p)
                        a32[c][p] = fmaf(w3[kx][c], seg[p + kx], a32[c][p]);
            }
        };

        compute(0, A);
        #pragma unroll
        for (int c = 0; c < 8; ++c) A[c] = *(const f32x4*)(bky[2] + (size_t)c * HW);
        compute(1, B);
        compute(2, A);

        #pragma unroll
        for (int p = 0; p < 4; ++p) {
            uint32 pk[4];
            #pragma unroll
            for (int i = 0; i < 4; ++i)
                pk[i] = f2bf_bits(a32[2 * i][p]) | (f2bf_bits(a32[2 * i + 1][p]) << 16);
            *(uint4*)&h1s[px0 + p][cin0] = make_uint4(pk[0], pk[1], pk[2], pk[3]);
        }
    }
    __syncthreads();

    // stage dw2/pw2 weights into LDS (overlaps MFMA phase; consumed in phase 3)
    for (int i = tid; i < 11 * C_HID; i += 512)
        wlds[i] = (i < 9 * C_HID) ? qdw2T[i] : qpw2[i - 9 * C_HID];

    // ---------- phase 2: MFMA pw1 ----------
    const int l15 = lane & 15, l4 = lane >> 4;
    const int wco = wave >> 2;          // 0..1: co half
    const int wpx = wave & 3;           // 0..3: 32-px quarter
    const int px0w = wpx << 5;
    const float bscale = scales[0];

    f32x4 acc[2][8];
    #pragma unroll
    for (int f = 0; f < 2; ++f)
        #pragma unroll
        for (int c = 0; c < 8; ++c) acc[f][c] = f32x4{0, 0, 0, 0};

    const bf16x8* BL = (const bf16x8*)Blin;

    #pragma unroll
    for (int ks = 0; ks < 4; ++ks) {
        bf16x8 bfrag[8];
        #pragma unroll
        for (int c = 0; c < 8; ++c)
            bfrag[c] = BL[(ks * 16 + wco * 8 + c) * 64 + lane];
        bf16x8 afrag[2];
        #pragma unroll
        for (int f = 0; f < 2; ++f)
            afrag[f] = *(const bf16x8*)&h1s[px0w + f * 16 + l15][ks * 32 + l4 * 8];
        #pragma unroll
        for (int f = 0; f < 2; ++f)
            #pragma unroll
            for (int c = 0; c < 8; ++c)
                acc[f][c] = __builtin_amdgcn_mfma_f32_16x16x32_bf16(
                    afrag[f], bfrag[c], acc[f][c], 0, 0, 0);
    }

    __syncthreads();   // all MFMA reads of h1s complete; smem becomes h2s

    // epilogue: scale+bias+ReLU, pack, write straight from accumulators to LDS
    #pragma unroll
    for (int f = 0; f < 2; ++f) {
        int pxb = px0w + f * 16 + l4 * 4;
        #pragma unroll
        for (int c = 0; c < 8; ++c) {
            int co = wco * 128 + c * 16 + l15;
            float bias = pb1[co];
            float v0 = fmaxf(fmaf(acc[f][c].x, bscale, bias), 0.0f);
            float v1 = fmaxf(fmaf(acc[f][c].y, bscale, bias), 0.0f);
            float v2 = fmaxf(fmaf(acc[f][c].z, bscale, bias), 0.0f);
            float v3 = fmaxf(fmaf(acc[f][c].w, bscale, bias), 0.0f);
            uint2 pk;
            pk.x = f2bf_bits(v0) | (f2bf_bits(v1) << 16);
            pk.y = f2bf_bits(v2) | (f2bf_bits(v3) << 16);
            *(uint2*)&h2s[co][pxb] = pk;
        }
    }
    __syncthreads();

    // ---------- phase 3: dw2 + pw2 partials (low-pressure tiling) ----------
    // pg = tid&31 -> 4 px; cg = tid>>5 -> 16 channels. Live set ~55 VGPRs.
    const int pg = tid & 31, cg = tid >> 5;
    const int px0p = pg << 2;

    float P[6][4];
    #pragma unroll
    for (int r = 0; r < 6; ++r)
        #pragma unroll
        for (int p = 0; p < 4; ++p) P[r][p] = 0.0f;

    #pragma unroll 4
    for (int c = 0; c < 16; ++c) {
        const int ch = (cg << 4) + c;
        uint2 mv = *(const uint2*)&h2s[ch][px0p];
        u16 lfu = (pg > 0)  ? h2s[ch][px0p - 1] : (u16)0;
        u16 rtu = (pg < 31) ? h2s[ch][px0p + 4] : (u16)0;
        float seg[6];
        seg[0] = bf_u16(lfu);
        seg[1] = bf_lo(mv.x); seg[2] = bf_hi(mv.x);
        seg[3] = bf_lo(mv.y); seg[4] = bf_hi(mv.y);
        seg[5] = bf_u16(rtu);
        float w9[9];
        #pragma unroll
        for (int t = 0; t < 9; ++t) w9[t] = wlds[t * C_HID + ch];
        float wA = wlds[9 * C_HID + ch], wB = wlds[10 * C_HID + ch];
        #pragma unroll
        for (int p = 0; p < 4; ++p) {
            float t0 = fmaf(w9[0], seg[p], fmaf(w9[1], seg[p + 1], w9[2] * seg[p + 2]));
            float t1 = fmaf(w9[3], seg[p], fmaf(w9[4], seg[p + 1], w9[5] * seg[p + 2]));
            float t2 = fmaf(w9[6], seg[p], fmaf(w9[7], seg[p + 1], w9[8] * seg[p + 2]));
            P[0][p] = fmaf(wA, t0, P[0][p]);
            P[1][p] = fmaf(wB, t0, P[1][p]);
            P[2][p] = fmaf(wA, t1, P[2][p]);
            P[3][p] = fmaf(wB, t1, P[3][p]);
            P[4][p] = fmaf(wA, t2, P[4][p]);
            P[5][p] = fmaf(wB, t2, P[5][p]);
        }
    }

    // fold the wave's two ch-groups (lanes xor 32)
    #pragma unroll
    for (int r = 0; r < 6; ++r)
        #pragma unroll
        for (int p = 0; p < 4; ++p)
            P[r][p] += __shfl_xor(P[r][p], 32, 64);

    __syncthreads();   // all h2s reads done; smem now Pbuf
    if (lane < 32) {
        #pragma unroll
        for (int r = 0; r < 6; ++r)
            *(f32x4*)&Pbuf[r * 1024 + wave * 128 + px0p] =
                f32x4{P[r][0], P[r][1], P[r][2], P[r][3]};
    }
    __syncthreads();

    for (int t = tid; t < 768; t += 512) {
        int r = t >> 7, px = t & 127;
        float v = 0.0f;
        #pragma unroll
        for (int w = 0; w < 8; ++w) v += Pbuf[r * 1024 + w * 128 + px];
        Pg[((size_t)(nb * HGT + y) * 6 + r) * WID + px] = v;
    }
}

// ============ gather: out[o][y] = consts + sum_ky P_{y+ky-1}[ky*2+o] ============
__global__ __launch_bounds__(512) void gather_out(
    const float* __restrict__ Pg, const float* __restrict__ pb2,
    const float* __restrict__ scales, float* __restrict__ out)
{
    int idx = blockIdx.x * 512 + threadIdx.x;
    int px = idx & 127;
    int yy = (idx >> 7) & 63;
    int o  = (idx >> 13) & 1;
    int nb = idx >> 14;
    float v = pb2[o] + scales[1 + o];
    #pragma unroll
    for (int ky = 0; ky < 3; ++ky) {
        int z = yy + ky - 1;   // cross-correlation: tap ky reads source row y+ky-1
        if (z >= 0 && z < HGT)
            v += Pg[((size_t)(nb * HGT + z) * 6 + ky * 2 + o) * WID + px];
    }
    out[idx] = v;
}

extern "C" void kernel_launch(void* const* d_in, const int* in_sizes, int n_in,
                              void* d_out, int out_size, void* d_ws, size_t ws_size,
                              hipStream_t stream) {
    const float* x   = (const float*)d_in[0];
    const float* dw1 = (const float*)d_in[1];
    const float* db1 = (const float*)d_in[2];
    const float* pw1 = (const float*)d_in[3];
    const float* pb1 = (const float*)d_in[4];
    const float* dw2 = (const float*)d_in[5];
    const float* db2 = (const float*)d_in[6];
    const float* pw2 = (const float*)d_in[7];
    const float* pb2 = (const float*)d_in[8];
    float* out = (float*)d_out;

    char* wsb = (char*)d_ws;
    u16*   Blin   = (u16*)wsb;                         // 65536 B
    float* qdw1T  = (float*)(wsb + 65536);             // 4608 B
    float* qdw2T  = (float*)(wsb + 65536 + 4608);      // 9216 B
    float* qpw2   = (float*)(wsb + 65536 + 4608 + 9216);          // 2048 B
    float* scales = (float*)(wsb + 65536 + 4608 + 9216 + 2048);   // 64 B
    float* Pg     = (float*)(wsb + 81920);             // 16*64*6*128*4 = 3 MB

    quant4_kernel<<<4, 1024, 0, stream>>>(dw1, pw1, dw2, pw2, db2,
                                          qdw1T, Blin, qdw2T, qpw2, scales);

    fused_main<<<NBATCH * HGT, 512, 0, stream>>>(
        x, qdw1T, db1, Blin, pb1, qdw2T, qpw2, scales, Pg);

    gather_out<<<512, 512, 0, stream>>>(Pg, pb2, scales, out);
}

// Round 16
// 63.165 us; speedup vs baseline: 1.2357x; 1.2357x over previous
//
#include <hip/hip_runtime.h>
#include <math.h>

#define C_IN  128
#define C_HID 256
#define HGT   64
#define WID   128
#define NBATCH 16
#define HW (HGT * WID)

typedef unsigned int   uint32;
typedef unsigned short u16;
typedef float f32x4  __attribute__((ext_vector_type(4)));
typedef short bf16x8 __attribute__((ext_vector_type(8)));

__device__ __forceinline__ uint32 f2bf_bits(float f) {
    uint32 u = __float_as_uint(f);
    u = (u + 0x7fff + ((u >> 16) & 1)) >> 16;   // RNE
    return u;
}
__device__ __forceinline__ float bf_lo(uint32 v) { return __uint_as_float(v << 16); }
__device__ __forceinline__ float bf_hi(uint32 v) { return __uint_as_float(v & 0xffff0000u); }

// ============ quant: per-tensor symmetric int8 fake-quant + repack ============
// 1024 threads; max phase uses f32x4 loads (all tensor sizes divisible by 4).
__global__ __launch_bounds__(1024) void quant4_kernel(
    const float* __restrict__ dw1, const float* __restrict__ pw1,
    const float* __restrict__ dw2, const float* __restrict__ pw2,
    const float* __restrict__ db2,
    float* __restrict__ qdw1T, u16* __restrict__ Blin,
    float* __restrict__ qdw2T, float* __restrict__ qpw2,
    float* __restrict__ scales)
{
    const float* w; int n;
    switch (blockIdx.x) {
        case 0:  w = dw1; n = C_IN * 9;    break;
        case 1:  w = pw1; n = C_HID * C_IN; break;
        case 2:  w = dw2; n = C_HID * 9;   break;
        default: w = pw2; n = 2 * C_HID;   break;
    }
    __shared__ float sm[1024];
    int tid = threadIdx.x;
    const f32x4* w4 = (const f32x4*)w;
    int n4 = n >> 2;
    float m = 0.0f;
    #pragma unroll 4
    for (int i = tid; i < n4; i += 1024) {
        f32x4 v = w4[i];
        m = fmaxf(m, fmaxf(fmaxf(fabsf(v.x), fabsf(v.y)),
                           fmaxf(fabsf(v.z), fabsf(v.w))));
    }
    sm[tid] = m;
    __syncthreads();
    for (int s = 512; s > 0; s >>= 1) {
        if (tid < s) sm[tid] = fmaxf(sm[tid], sm[tid + s]);
        __syncthreads();
    }
    const float scale = sm[0] / 127.0f;

    if (blockIdx.x == 0) {
        for (int i = tid; i < C_IN * 9; i += 1024) {
            int t = i >> 7, cin = i & 127;
            float v = rintf(dw1[cin * 9 + t] / scale);
            v = fminf(fmaxf(v, -128.0f), 127.0f);
            qdw1T[i] = v * scale;
        }
    } else if (blockIdx.x == 1) {
        if (tid == 0) scales[0] = scale;
        // slot s = (kstep*16 + cofrag)*64 + lane; each slot = 8 bf16 (16B)
        #pragma unroll
        for (int i = tid; i < 4096; i += 1024) {
            int kstep = i >> 10;
            int cf    = (i >> 6) & 15;
            int l     = i & 63;
            int co    = cf * 16 + (l & 15);
            int k0    = kstep * 32 + ((l >> 4) << 3);
            const float* src = pw1 + (size_t)co * C_IN + k0;
            f32x4 a = *(const f32x4*)src;
            f32x4 b = *(const f32x4*)(src + 4);
            float vv[8] = {a.x, a.y, a.z, a.w, b.x, b.y, b.z, b.w};
            uint32 pk[4];
            #pragma unroll
            for (int p = 0; p < 4; ++p) {
                float v0 = fminf(fmaxf(rintf(vv[2 * p]     / scale), -128.0f), 127.0f);
                float v1 = fminf(fmaxf(rintf(vv[2 * p + 1] / scale), -128.0f), 127.0f);
                pk[p] = f2bf_bits(v0) | (f2bf_bits(v1) << 16);   // ints exact in bf16
            }
            ((uint4*)Blin)[i] = make_uint4(pk[0], pk[1], pk[2], pk[3]);
        }
    } else if (blockIdx.x == 2) {
        for (int i = tid; i < C_HID * 9; i += 1024) {
            int t = i >> 8, ch = i & 255;
            float v = rintf(dw2[ch * 9 + t] / scale);
            v = fminf(fmaxf(v, -128.0f), 127.0f);
            qdw2T[i] = v * scale;
        }
    } else {
        if (tid < 2 * C_HID) {
            float v = rintf(pw2[tid] / scale);
            v = fminf(fmaxf(v, -128.0f), 127.0f);
            qpw2[tid] = v * scale;
        }
        // dotbias[o] = sum_ch qpw2[o][ch] * db2[ch]  (dw2 bias folded through pw2)
        #pragma unroll
        for (int o = 0; o < 2; ++o) {
            __syncthreads();
            if (tid < 256) {
                float qv = rintf(pw2[o * C_HID + tid] / scale);
                qv = fminf(fmaxf(qv, -128.0f), 127.0f) * scale;
                sm[tid] = qv * db2[tid];
            }
            __syncthreads();
            for (int s = 128; s > 0; s >>= 1) {
                if (tid < s) sm[tid] += sm[tid + s];
                __syncthreads();
            }
            if (tid == 0) scales[1 + o] = sm[0];
        }
    }
}

// ============ fused: dw1 + MFMA pw1 + ReLU + dw2/pw2 partials -> Pg ============
// R14 exact structure (proven best): shfl-halo phase 1, single-buffer loads,
// launch_bounds (512,4) -> 64 VGPR, 2 blocks/CU, no spill.
// R16 delta: phase-3 halo values via shfl instead of scalar LDS reads.
__global__ __launch_bounds__(512, 4) void fused_main(
    const float* __restrict__ x,
    const float* __restrict__ qdw1T, const float* __restrict__ db1,
    const u16* __restrict__ Blin, const float* __restrict__ pb1,
    const float* __restrict__ qdw2T, const float* __restrict__ qpw2,
    const float* __restrict__ scales,
    float* __restrict__ Pg)
{
    __shared__ __align__(16) unsigned char smem_raw[C_HID * 132 * 2];   // 67584 B
    __shared__ float wlds[9 * C_HID + 2 * C_HID];                        // 11264 B
    u16 (*h1s)[136] = (u16 (*)[136])smem_raw;   // phase 1-2: bf16 A-tile (34.8 KB)
    u16 (*h2s)[132] = (u16 (*)[132])smem_raw;   // epilogue+phase 3: full h2 row
    float* Pbuf = (float*)smem_raw;             // phase 4: [6][8][128] reduce buffer

    const int bid = blockIdx.x;
    const int swz = (bid & 7) * 128 + (bid >> 3);   // XCD-bijective
    const int nb  = swz >> 6;
    const int y   = swz & 63;                        // this block's h2 row z
    const int tid = threadIdx.x;
    const int wave = tid >> 6, lane = tid & 63;

    // ---------- phase 1: depthwise 1 -> h1s (8 coalesced loads/ky; halo via shfl) ----------
    {
        const int q = tid & 31, g = tid >> 5;
        const int px0 = q << 2, cin0 = g << 3;
        // lane = (g&1)*32 + q: thread q-1/q+1 are lane-1/lane+1; the q=0 / q=31
        // masks exactly cover the half-wave boundary, so cross-group shuffle
        // values are always discarded.

        f32x4 bia = *(const f32x4*)(db1 + cin0);
        f32x4 bib = *(const f32x4*)(db1 + cin0 + 4);
        float a32[8][4];
        #pragma unroll
        for (int c = 0; c < 8; ++c) {
            float b = (c < 4) ? ((const float*)&bia)[c] : ((const float*)&bib)[c - 4];
            #pragma unroll
            for (int p = 0; p < 4; ++p) a32[c][p] = b;
        }

        #pragma unroll
        for (int ky = 0; ky < 3; ++ky) {
            int yy = y + ky - 1;
            if (yy < 0 || yy >= HGT) continue;
            const float* xbase = x + (((size_t)nb * C_IN + cin0) * HGT + yy) * WID;

            // 8 independent coalesced 16B loads (the only VMEM in this ky)
            f32x4 mid[8];
            #pragma unroll
            for (int c = 0; c < 8; ++c)
                mid[c] = *(const f32x4*)(xbase + (size_t)c * HW + px0);

            float w3[3][8];
            #pragma unroll
            for (int kx = 0; kx < 3; ++kx) {
                f32x4 wa = *(const f32x4*)(qdw1T + (ky * 3 + kx) * C_IN + cin0);
                f32x4 wb = *(const f32x4*)(qdw1T + (ky * 3 + kx) * C_IN + cin0 + 4);
                w3[kx][0] = wa.x; w3[kx][1] = wa.y; w3[kx][2] = wa.z; w3[kx][3] = wa.w;
                w3[kx][4] = wb.x; w3[kx][5] = wb.y; w3[kx][6] = wb.z; w3[kx][7] = wb.w;
            }

            #pragma unroll
            for (int c = 0; c < 8; ++c) {
                float lf = __shfl_up(mid[c].w, 1);     // lane-1's px0-1
                float rt = __shfl_down(mid[c].x, 1);   // lane+1's px0+4
                lf = (q > 0)  ? lf : 0.0f;
                rt = (q < 31) ? rt : 0.0f;
                float seg[6] = {lf, mid[c].x, mid[c].y, mid[c].z, mid[c].w, rt};
                #pragma unroll
                for (int kx = 0; kx < 3; ++kx)
                    #pragma unroll
                    for (int p = 0; p < 4; ++p)
                        a32[c][p] = fmaf(w3[kx][c], seg[p + kx], a32[c][p]);
            }
        }

        #pragma unroll
        for (int p = 0; p < 4; ++p) {
            uint32 pk[4];
            #pragma unroll
            for (int i = 0; i < 4; ++i)
                pk[i] = f2bf_bits(a32[2 * i][p]) | (f2bf_bits(a32[2 * i + 1][p]) << 16);
            *(uint4*)&h1s[px0 + p][cin0] = make_uint4(pk[0], pk[1], pk[2], pk[3]);
        }
    }
    __syncthreads();

    // stage dw2/pw2 weights into LDS (overlaps MFMA phase; consumed in phase 3)
    for (int i = tid; i < 11 * C_HID; i += 512)
        wlds[i] = (i < 9 * C_HID) ? qdw2T[i] : qpw2[i - 9 * C_HID];

    // ---------- phase 2: MFMA pw1 ----------
    const int l15 = lane & 15, l4 = lane >> 4;
    const int wco = wave >> 2;          // 0..1: co half
    const int wpx = wave & 3;           // 0..3: 32-px quarter
    const int px0w = wpx << 5;
    const float bscale = scales[0];

    f32x4 acc[2][8];
    #pragma unroll
    for (int f = 0; f < 2; ++f)
        #pragma unroll
        for (int c = 0; c < 8; ++c) acc[f][c] = f32x4{0, 0, 0, 0};

    const bf16x8* BL = (const bf16x8*)Blin;

    #pragma unroll
    for (int ks = 0; ks < 4; ++ks) {
        bf16x8 bfrag[8];
        #pragma unroll
        for (int c = 0; c < 8; ++c)
            bfrag[c] = BL[(ks * 16 + wco * 8 + c) * 64 + lane];
        bf16x8 afrag[2];
        #pragma unroll
        for (int f = 0; f < 2; ++f)
            afrag[f] = *(const bf16x8*)&h1s[px0w + f * 16 + l15][ks * 32 + l4 * 8];
        #pragma unroll
        for (int f = 0; f < 2; ++f)
            #pragma unroll
            for (int c = 0; c < 8; ++c)
                acc[f][c] = __builtin_amdgcn_mfma_f32_16x16x32_bf16(
                    afrag[f], bfrag[c], acc[f][c], 0, 0, 0);
    }

    __syncthreads();   // all MFMA reads of h1s complete; smem becomes h2s

    // epilogue: scale+bias+ReLU, pack, write straight from accumulators to LDS
    #pragma unroll
    for (int f = 0; f < 2; ++f) {
        int pxb = px0w + f * 16 + l4 * 4;
        #pragma unroll
        for (int c = 0; c < 8; ++c) {
            int co = wco * 128 + c * 16 + l15;
            float bias = pb1[co];
            float v0 = fmaxf(fmaf(acc[f][c].x, bscale, bias), 0.0f);
            float v1 = fmaxf(fmaf(acc[f][c].y, bscale, bias), 0.0f);
            float v2 = fmaxf(fmaf(acc[f][c].z, bscale, bias), 0.0f);
            float v3 = fmaxf(fmaf(acc[f][c].w, bscale, bias), 0.0f);
            uint2 pk;
            pk.x = f2bf_bits(v0) | (f2bf_bits(v1) << 16);
            pk.y = f2bf_bits(v2) | (f2bf_bits(v3) << 16);
            *(uint2*)&h2s[co][pxb] = pk;
        }
    }
    __syncthreads();

    // ---------- phase 3: dw2 + pw2 partials (low-pressure tiling; halo via shfl) ----------
    // pg = tid&31 -> 4 px; cg = tid>>5 -> 16 channels. lane = (cg&1)*32 + pg,
    // so pg-neighbors are lane-neighbors and pg=0/31 masks cover half-wave edges.
    const int pg = tid & 31, cg = tid >> 5;
    const int px0p = pg << 2;

    float P[6][4];
    #pragma unroll
    for (int r = 0; r < 6; ++r)
        #pragma unroll
        for (int p = 0; p < 4; ++p) P[r][p] = 0.0f;

    #pragma unroll 4
    for (int c = 0; c < 16; ++c) {
        const int ch = (cg << 4) + c;
        uint2 mv = *(const uint2*)&h2s[ch][px0p];
        float e0 = bf_lo(mv.x), e1 = bf_hi(mv.x);
        float e2 = bf_lo(mv.y), e3 = bf_hi(mv.y);
        float lf = __shfl_up(e3, 1);       // lane-1's px0p+3 = our px0p-1
        float rt = __shfl_down(e0, 1);     // lane+1's px0p   = our px0p+4
        lf = (pg > 0)  ? lf : 0.0f;
        rt = (pg < 31) ? rt : 0.0f;
        float seg[6] = {lf, e0, e1, e2, e3, rt};
        float w9[9];
        #pragma unroll
        for (int t = 0; t < 9; ++t) w9[t] = wlds[t * C_HID + ch];
        float wA = wlds[9 * C_HID + ch], wB = wlds[10 * C_HID + ch];
        #pragma unroll
        for (int p = 0; p < 4; ++p) {
            float t0 = fmaf(w9[0], seg[p], fmaf(w9[1], seg[p + 1], w9[2] * seg[p + 2]));
            float t1 = fmaf(w9[3], seg[p], fmaf(w9[4], seg[p + 1], w9[5] * seg[p + 2]));
            float t2 = fmaf(w9[6], seg[p], fmaf(w9[7], seg[p + 1], w9[8] * seg[p + 2]));
            P[0][p] = fmaf(wA, t0, P[0][p]);
            P[1][p] = fmaf(wB, t0, P[1][p]);
            P[2][p] = fmaf(wA, t1, P[2][p]);
            P[3][p] = fmaf(wB, t1, P[3][p]);
            P[4][p] = fmaf(wA, t2, P[4][p]);
            P[5][p] = fmaf(wB, t2, P[5][p]);
        }
    }

    // fold the wave's two ch-groups (lanes xor 32)
    #pragma unroll
    for (int r = 0; r < 6; ++r)
        #pragma unroll
        for (int p = 0; p < 4; ++p)
            P[r][p] += __shfl_xor(P[r][p], 32, 64);

    __syncthreads();   // all h2s reads done; smem now Pbuf
    if (lane < 32) {
        #pragma unroll
        for (int r = 0; r < 6; ++r)
            *(f32x4*)&Pbuf[r * 1024 + wave * 128 + px0p] =
                f32x4{P[r][0], P[r][1], P[r][2], P[r][3]};
    }
    __syncthreads();

    for (int t = tid; t < 768; t += 512) {
        int r = t >> 7, px = t & 127;
        float v = 0.0f;
        #pragma unroll
        for (int w = 0; w < 8; ++w) v += Pbuf[r * 1024 + w * 128 + px];
        Pg[((size_t)(nb * HGT + y) * 6 + r) * WID + px] = v;
    }
}

// ============ gather: out[o][y] = consts + sum_ky P_{y+ky-1}[ky*2+o] ============
__global__ __launch_bounds__(512) void gather_out(
    const float* __restrict__ Pg, const float* __restrict__ pb2,
    const float* __restrict__ scales, float* __restrict__ out)
{
    int idx = blockIdx.x * 512 + threadIdx.x;
    int px = idx & 127;
    int yy = (idx >> 7) & 63;
    int o  = (idx >> 13) & 1;
    int nb = idx >> 14;
    float v = pb2[o] + scales[1 + o];
    #pragma unroll
    for (int ky = 0; ky < 3; ++ky) {
        int z = yy + ky - 1;   // cross-correlation: tap ky reads source row y+ky-1
        if (z >= 0 && z < HGT)
            v += Pg[((size_t)(nb * HGT + z) * 6 + ky * 2 + o) * WID + px];
    }
    out[idx] = v;
}

extern "C" void kernel_launch(void* const* d_in, const int* in_sizes, int n_in,
                              void* d_out, int out_size, void* d_ws, size_t ws_size,
                              hipStream_t stream) {
    const float* x   = (const float*)d_in[0];
    const float* dw1 = (const float*)d_in[1];
    const float* db1 = (const float*)d_in[2];
    const float* pw1 = (const float*)d_in[3];
    const float* pb1 = (const float*)d_in[4];
    const float* dw2 = (const float*)d_in[5];
    const float* db2 = (const float*)d_in[6];
    const float* pw2 = (const float*)d_in[7];
    const float* pb2 = (const float*)d_in[8];
    float* out = (float*)d_out;

    char* wsb = (char*)d_ws;
    u16*   Blin   = (u16*)wsb;                         // 65536 B
    float* qdw1T  = (float*)(wsb + 65536);             // 4608 B
    float* qdw2T  = (float*)(wsb + 65536 + 4608);      // 9216 B
    float* qpw2   = (float*)(wsb + 65536 + 4608 + 9216);          // 2048 B
    float* scales = (float*)(wsb + 65536 + 4608 + 9216 + 2048);   // 64 B
    float* Pg     = (float*)(wsb + 81920);             // 16*64*6*128*4 = 3 MB

    quant4_kernel<<<4, 1024, 0, stream>>>(dw1, pw1, dw2, pw2, db2,
                                          qdw1T, Blin, qdw2T, qpw2, scales);

    fused_main<<<NBATCH * HGT, 512, 0, stream>>>(
        x, qdw1T, db1, Blin, pb1, qdw2T, qpw2, scales, Pg);

    gather_out<<<512, 512, 0, stream>>>(Pg, pb2, scales, out);
}

// Round 17
// 48.374 us; speedup vs baseline: 1.6136x; 1.3058x over previous
//
#include <hip/hip_runtime.h>
#include <math.h>

#define C_IN  128
#define C_HID 256
#define HGT   64
#define WID   128
#define NBATCH 16
#define HW (HGT * WID)

typedef unsigned int   uint32;
typedef unsigned short u16;
typedef float f32x4  __attribute__((ext_vector_type(4)));
typedef short bf16x8 __attribute__((ext_vector_type(8)));

__device__ __forceinline__ uint32 f2bf_bits(float f) {
    uint32 u = __float_as_uint(f);
    u = (u + 0x7fff + ((u >> 16) & 1)) >> 16;   // RNE
    return u;
}
__device__ __forceinline__ float qclip(float v) {
    return fminf(fmaxf(v, -128.0f), 127.0f);
}

// ============ quant: per-tensor symmetric int8 fake-quant + repack ============
// block 0: dw1 -> qdw1T[9][128]
// block 1: pw1 -> Blin (MFMA-frag bf16 ints) + scales[0]
// block 2: (unused legacy)
// block 3: pw2+dw2 -> W18lin (combined dw2*pw2 weights, bf16 MFMA-frag) + dotbias
__global__ __launch_bounds__(1024) void quant4_kernel(
    const float* __restrict__ dw1, const float* __restrict__ pw1,
    const float* __restrict__ dw2, const float* __restrict__ pw2,
    const float* __restrict__ db2,
    float* __restrict__ qdw1T, u16* __restrict__ Blin,
    u16* __restrict__ W18lin, float* __restrict__ scales)
{
    const float* w; int n;
    switch (blockIdx.x) {
        case 0:  w = dw1; n = C_IN * 9;    break;
        case 1:  w = pw1; n = C_HID * C_IN; break;
        case 2:  w = dw2; n = C_HID * 9;   break;
        default: w = pw2; n = 2 * C_HID;   break;
    }
    __shared__ float sm[1024];
    int tid = threadIdx.x;
    const f32x4* w4 = (const f32x4*)w;
    int n4 = n >> 2;
    float m = 0.0f;
    #pragma unroll 4
    for (int i = tid; i < n4; i += 1024) {
        f32x4 v = w4[i];
        m = fmaxf(m, fmaxf(fmaxf(fabsf(v.x), fabsf(v.y)),
                           fmaxf(fabsf(v.z), fabsf(v.w))));
    }
    sm[tid] = m;
    __syncthreads();
    for (int s = 512; s > 0; s >>= 1) {
        if (tid < s) sm[tid] = fmaxf(sm[tid], sm[tid + s]);
        __syncthreads();
    }
    const float scale = sm[0] / 127.0f;

    if (blockIdx.x == 0) {
        for (int i = tid; i < C_IN * 9; i += 1024) {
            int t = i >> 7, cin = i & 127;
            float v = qclip(rintf(dw1[cin * 9 + t] / scale));
            qdw1T[i] = v * scale;
        }
    } else if (blockIdx.x == 1) {
        if (tid == 0) scales[0] = scale;
        // slot s = (kstep*16 + cofrag)*64 + lane; each slot = 8 bf16 (16B)
        #pragma unroll
        for (int i = tid; i < 4096; i += 1024) {
            int kstep = i >> 10;
            int cf    = (i >> 6) & 15;
            int l     = i & 63;
            int co    = cf * 16 + (l & 15);
            int k0    = kstep * 32 + ((l >> 4) << 3);
            const float* src = pw1 + (size_t)co * C_IN + k0;
            f32x4 a = *(const f32x4*)src;
            f32x4 b = *(const f32x4*)(src + 4);
            float vv[8] = {a.x, a.y, a.z, a.w, b.x, b.y, b.z, b.w};
            uint32 pk[4];
            #pragma unroll
            for (int p = 0; p < 4; ++p) {
                float v0 = qclip(rintf(vv[2 * p]     / scale));
                float v1 = qclip(rintf(vv[2 * p + 1] / scale));
                pk[p] = f2bf_bits(v0) | (f2bf_bits(v1) << 16);   // ints exact in bf16
            }
            ((uint4*)Blin)[i] = make_uint4(pk[0], pk[1], pk[2], pk[3]);
        }
    } else if (blockIdx.x == 2) {
        // legacy no-op (dw2 handled in block 3)
    } else {
        const float s_p = scale;   // pw2 scale from the generic max above
        __syncthreads();           // sm[0] consumed by all; safe to reuse sm

        // second reduction: max|dw2| (2304 = 576 f32x4)
        const f32x4* d4 = (const f32x4*)dw2;
        float md = 0.0f;
        for (int i = tid; i < 576; i += 1024) {
            f32x4 v = d4[i];
            md = fmaxf(md, fmaxf(fmaxf(fabsf(v.x), fabsf(v.y)),
                                 fmaxf(fabsf(v.z), fabsf(v.w))));
        }
        sm[tid] = md;
        __syncthreads();
        for (int s = 512; s > 0; s >>= 1) {
            if (tid < s) sm[tid] = fmaxf(sm[tid], sm[tid + s]);
            __syncthreads();
        }
        const float s_d = sm[0] / 127.0f;

        // W18lin: slot = (ks*2 + jt)*64 + lane; j = jt*16 + (lane&15),
        // ch0 = ks*32 + (lane>>4)*8. W18[j][ch] = qdw2(ch, j>>1) * qpw2(j&1, ch).
        {
            int ks  = tid >> 7;
            int jt  = (tid >> 6) & 1;
            int l   = tid & 63;
            int j   = jt * 16 + (l & 15);
            int ch0 = ks * 32 + ((l >> 4) << 3);
            uint32 pk[4] = {0, 0, 0, 0};
            if (j < 18) {
                int t9 = j >> 1, o = j & 1;
                float wv[8];
                #pragma unroll
                for (int p = 0; p < 8; ++p) {
                    int ch = ch0 + p;
                    float qd = qclip(rintf(dw2[ch * 9 + t9] / s_d)) * s_d;
                    float qp = qclip(rintf(pw2[o * C_HID + ch] / s_p)) * s_p;
                    wv[p] = qd * qp;
                }
                #pragma unroll
                for (int p = 0; p < 4; ++p)
                    pk[p] = f2bf_bits(wv[2 * p]) | (f2bf_bits(wv[2 * p + 1]) << 16);
            }
            ((uint4*)W18lin)[tid] = make_uint4(pk[0], pk[1], pk[2], pk[3]);
        }

        // dotbias[o] = sum_ch qpw2[o][ch] * db2[ch]
        #pragma unroll
        for (int o = 0; o < 2; ++o) {
            __syncthreads();
            if (tid < 256) {
                float qv = qclip(rintf(pw2[o * C_HID + tid] / s_p)) * s_p;
                sm[tid] = qv * db2[tid];
            }
            __syncthreads();
            for (int s = 128; s > 0; s >>= 1) {
                if (tid < s) sm[tid] += sm[tid + s];
                __syncthreads();
            }
            if (tid == 0) scales[1 + o] = sm[0];
        }
    }
}

// ============ fused: dw1 + MFMA pw1 + ReLU + MFMA dw2/pw2 -> Pg ============
// R14 phases 1-2; phase 3 is now a 128x32 (K=256) MFMA GEMM vs W18.
__global__ __launch_bounds__(512, 4) void fused_main(
    const float* __restrict__ x,
    const float* __restrict__ qdw1T, const float* __restrict__ db1,
    const u16* __restrict__ Blin, const float* __restrict__ pb1,
    const u16* __restrict__ W18lin,
    const float* __restrict__ scales,
    float* __restrict__ Pg)
{
    __shared__ __align__(16) unsigned char smem_raw[C_HID * 132 * 2];   // 67584 B
    __shared__ float Ml[128][20];                                        // 10240 B
    u16 (*h1s)[136]  = (u16 (*)[136])smem_raw;   // phase 1-2: bf16 A-tile (px-major, k contig)
    u16 (*h2pm)[264] = (u16 (*)[264])smem_raw;   // epilogue+phase 3: h2 px-major [px][ch]

    const int bid = blockIdx.x;
    const int swz = (bid & 7) * 128 + (bid >> 3);   // XCD-bijective
    const int nb  = swz >> 6;
    const int y   = swz & 63;                        // this block's h2 row z
    const int tid = threadIdx.x;
    const int wave = tid >> 6, lane = tid & 63;

    // ---------- phase 1: depthwise 1 -> h1s (8 coalesced loads/ky; halo via shfl) ----------
    {
        const int q = tid & 31, g = tid >> 5;
        const int px0 = q << 2, cin0 = g << 3;
        // lane = (g&1)*32 + q: q boundaries coincide with half-wave boundaries,
        // so cross-boundary shuffle values are always masked to zero.

        f32x4 bia = *(const f32x4*)(db1 + cin0);
        f32x4 bib = *(const f32x4*)(db1 + cin0 + 4);
        float a32[8][4];
        #pragma unroll
        for (int c = 0; c < 8; ++c) {
            float b = (c < 4) ? ((const float*)&bia)[c] : ((const float*)&bib)[c - 4];
            #pragma unroll
            for (int p = 0; p < 4; ++p) a32[c][p] = b;
        }

        #pragma unroll
        for (int ky = 0; ky < 3; ++ky) {
            int yy = y + ky - 1;
            if (yy < 0 || yy >= HGT) continue;
            const float* xbase = x + (((size_t)nb * C_IN + cin0) * HGT + yy) * WID;

            f32x4 mid[8];
            #pragma unroll
            for (int c = 0; c < 8; ++c)
                mid[c] = *(const f32x4*)(xbase + (size_t)c * HW + px0);

            float w3[3][8];
            #pragma unroll
            for (int kx = 0; kx < 3; ++kx) {
                f32x4 wa = *(const f32x4*)(qdw1T + (ky * 3 + kx) * C_IN + cin0);
                f32x4 wb = *(const f32x4*)(qdw1T + (ky * 3 + kx) * C_IN + cin0 + 4);
                w3[kx][0] = wa.x; w3[kx][1] = wa.y; w3[kx][2] = wa.z; w3[kx][3] = wa.w;
                w3[kx][4] = wb.x; w3[kx][5] = wb.y; w3[kx][6] = wb.z; w3[kx][7] = wb.w;
            }

            #pragma unroll
            for (int c = 0; c < 8; ++c) {
                float lf = __shfl_up(mid[c].w, 1);     // lane-1's px0-1
                float rt = __shfl_down(mid[c].x, 1);   // lane+1's px0+4
                lf = (q > 0)  ? lf : 0.0f;
                rt = (q < 31) ? rt : 0.0f;
                float seg[6] = {lf, mid[c].x, mid[c].y, mid[c].z, mid[c].w, rt};
                #pragma unroll
                for (int kx = 0; kx < 3; ++kx)
                    #pragma unroll
                    for (int p = 0; p < 4; ++p)
                        a32[c][p] = fmaf(w3[kx][c], seg[p + kx], a32[c][p]);
            }
        }

        #pragma unroll
        for (int p = 0; p < 4; ++p) {
            uint32 pk[4];
            #pragma unroll
            for (int i = 0; i < 4; ++i)
                pk[i] = f2bf_bits(a32[2 * i][p]) | (f2bf_bits(a32[2 * i + 1][p]) << 16);
            *(uint4*)&h1s[px0 + p][cin0] = make_uint4(pk[0], pk[1], pk[2], pk[3]);
        }
    }
    __syncthreads();

    // ---------- phase 2: MFMA pw1 ----------
    const int l15 = lane & 15, l4 = lane >> 4;
    const int wco = wave >> 2;          // 0..1: co half
    const int wpx = wave & 3;           // 0..3: 32-px quarter
    const int px0w = wpx << 5;
    const float bscale = scales[0];

    f32x4 acc[2][8];
    #pragma unroll
    for (int f = 0; f < 2; ++f)
        #pragma unroll
        for (int c = 0; c < 8; ++c) acc[f][c] = f32x4{0, 0, 0, 0};

    const bf16x8* BL = (const bf16x8*)Blin;

    #pragma unroll
    for (int ks = 0; ks < 4; ++ks) {
        bf16x8 bfrag[8];
        #pragma unroll
        for (int c = 0; c < 8; ++c)
            bfrag[c] = BL[(ks * 16 + wco * 8 + c) * 64 + lane];
        bf16x8 afrag[2];
        #pragma unroll
        for (int f = 0; f < 2; ++f)
            afrag[f] = *(const bf16x8*)&h1s[px0w + f * 16 + l15][ks * 32 + l4 * 8];
        #pragma unroll
        for (int f = 0; f < 2; ++f)
            #pragma unroll
            for (int c = 0; c < 8; ++c)
                acc[f][c] = __builtin_amdgcn_mfma_f32_16x16x32_bf16(
                    afrag[f], bfrag[c], acc[f][c], 0, 0, 0);
    }

    __syncthreads();   // all MFMA reads of h1s complete; smem becomes h2pm

    // epilogue: scale+bias+ReLU, pack, write px-major [px][ch] (b16 writes)
    #pragma unroll
    for (int f = 0; f < 2; ++f) {
        int pxb = px0w + f * 16 + l4 * 4;
        #pragma unroll
        for (int c = 0; c < 8; ++c) {
            int co = wco * 128 + c * 16 + l15;
            float bias = pb1[co];
            float v0 = fmaxf(fmaf(acc[f][c].x, bscale, bias), 0.0f);
            float v1 = fmaxf(fmaf(acc[f][c].y, bscale, bias), 0.0f);
            float v2 = fmaxf(fmaf(acc[f][c].z, bscale, bias), 0.0f);
            float v3 = fmaxf(fmaf(acc[f][c].w, bscale, bias), 0.0f);
            h2pm[pxb + 0][co] = (u16)f2bf_bits(v0);
            h2pm[pxb + 1][co] = (u16)f2bf_bits(v1);
            h2pm[pxb + 2][co] = (u16)f2bf_bits(v2);
            h2pm[pxb + 3][co] = (u16)f2bf_bits(v3);
        }
    }
    __syncthreads();

    // ---------- phase 3: MFMA M[128px][32j] = h2pm[128][256] x W18^T ----------
    // wave w owns px-tile [w*16, w*16+16)
    {
        const int px0t = wave << 4;
        const bf16x8* WL = (const bf16x8*)W18lin;

        f32x4 acc2[2];
        acc2[0] = f32x4{0, 0, 0, 0};
        acc2[1] = f32x4{0, 0, 0, 0};

        #pragma unroll 2
        for (int ks = 0; ks < 8; ++ks) {
            bf16x8 af = *(const bf16x8*)&h2pm[px0t + l15][ks * 32 + l4 * 8];
            bf16x8 b0 = WL[(ks * 2 + 0) * 64 + lane];
            bf16x8 b1 = WL[(ks * 2 + 1) * 64 + lane];
            acc2[0] = __builtin_amdgcn_mfma_f32_16x16x32_bf16(af, b0, acc2[0], 0, 0, 0);
            acc2[1] = __builtin_amdgcn_mfma_f32_16x16x32_bf16(af, b1, acc2[1], 0, 0, 0);
        }

        // D layout: col = lane&15 (j), row = l4*4 + i (px within tile)
        #pragma unroll
        for (int i = 0; i < 4; ++i)
            Ml[px0t + l4 * 4 + i][l15] = acc2[0][i];
        if (l15 < 2) {
            #pragma unroll
            for (int i = 0; i < 4; ++i)
                Ml[px0t + l4 * 4 + i][16 + l15] = acc2[1][i];
        }
    }
    __syncthreads();

    // ---------- gather: P_z[ky*2+o][px] = sum_kx M[px+kx-1][(ky*3+kx)*2+o] ----------
    for (int t = tid; t < 768; t += 512) {
        int r = t >> 7, px = t & 127;
        int ky = r >> 1, o = r & 1;
        float v = 0.0f;
        #pragma unroll
        for (int kx = 0; kx < 3; ++kx) {
            int pxs = px + kx - 1;
            if (pxs >= 0 && pxs < WID)
                v += Ml[pxs][(ky * 3 + kx) * 2 + o];
        }
        Pg[((size_t)(nb * HGT + y) * 6 + r) * WID + px] = v;
    }
}

// ============ gather: out[o][y] = consts + sum_ky P_{y+ky-1}[ky*2+o] ============
__global__ __launch_bounds__(512) void gather_out(
    const float* __restrict__ Pg, const float* __restrict__ pb2,
    const float* __restrict__ scales, float* __restrict__ out)
{
    int idx = blockIdx.x * 512 + threadIdx.x;
    int px = idx & 127;
    int yy = (idx >> 7) & 63;
    int o  = (idx >> 13) & 1;
    int nb = idx >> 14;
    float v = pb2[o] + scales[1 + o];
    #pragma unroll
    for (int ky = 0; ky < 3; ++ky) {
        int z = yy + ky - 1;   // cross-correlation: tap ky reads source row y+ky-1
        if (z >= 0 && z < HGT)
            v += Pg[((size_t)(nb * HGT + z) * 6 + ky * 2 + o) * WID + px];
    }
    out[idx] = v;
}

extern "C" void kernel_launch(void* const* d_in, const int* in_sizes, int n_in,
                              void* d_out, int out_size, void* d_ws, size_t ws_size,
                              hipStream_t stream) {
    const float* x   = (const float*)d_in[0];
    const float* dw1 = (const float*)d_in[1];
    const float* db1 = (const float*)d_in[2];
    const float* pw1 = (const float*)d_in[3];
    const float* pb1 = (const float*)d_in[4];
    const float* dw2 = (const float*)d_in[5];
    const float* db2 = (const float*)d_in[6];
    const float* pw2 = (const float*)d_in[7];
    const float* pb2 = (const float*)d_in[8];
    float* out = (float*)d_out;

    char* wsb = (char*)d_ws;
    u16*   Blin   = (u16*)wsb;                          // 65536 B
    float* qdw1T  = (float*)(wsb + 65536);              // 4608 B
    float* scales = (float*)(wsb + 65536 + 4608);       // 64 B
    u16*   W18lin = (u16*)(wsb + 65536 + 4608 + 64);    // 16384 B
    float* Pg     = (float*)(wsb + 98304);              // 16*64*6*128*4 = 3 MB

    quant4_kernel<<<4, 1024, 0, stream>>>(dw1, pw1, dw2, pw2, db2,
                                          qdw1T, Blin, W18lin, scales);

    fused_main<<<NBATCH * HGT, 512, 0, stream>>>(
        x, qdw1T, db1, Blin, pb1, W18lin, scales, Pg);

    gather_out<<<512, 512, 0, stream>>>(Pg, pb2, scales, out);
}